// Round 7
// baseline (25.274 us; speedup 1.0000x reference)
//
#include <hip/hip_runtime.h>

// LocalLinearLayer, SINGLE fused kernel: banded bf16 MFMA with
// register-baked A-fragments and operand-swapped MFMA for x4 stores.
//
// out[b,o,c] = bias[o] + sum_{j=0..24} W[o, o+j] * xp[b, o+j, c]
// xp[q] = x[q] (q<12), x[q-12] (12<=q<4108), x[q-24] (q>=4108)
//
// Per 16-output tile at o0, kappa in [0,64):
//   out[o0+j'][c] = sum_kappa Wb[j'][kappa] * xp[o0+kappa][c]
//   Wb[j'][kappa] = W[o0+j', kappa-j'] if 0<=kappa-j'<25 else 0
// MFMA (16x16x32 bf16) with A = x-fragment (row=channel), B = W-fragment
// (col=output): D[row=ch][col=o]. Lane (m,quad) then holds 4 CONSECUTIVE
// channels of output row o0+m -> one dwordx4 store per acc.
// W-fragment: lane (m,quad) holds W[o0+m][cch*32+quad*8+e-m], baked in
// registers from 8 clamped+masked scalar loads (W band is L2-resident,
// reused 32x across batches; tile-major grid keeps reuse on-XCD).

typedef __attribute__((ext_vector_type(8))) short short8;
typedef __attribute__((ext_vector_type(4))) float f32x4;

constexpr int Lseq = 4096;
constexpr int C    = 64;
constexpr int WIN  = 25;
constexpr int PAD  = 12;
constexpr int O_B  = 128;          // outputs per block (4 waves x 2 tiles x 16)
constexpr int PWIN = 176;          // taps staged (128 + 48 halo)
constexpr int PLX  = 184;          // x_lds row stride (shorts); non-pow2 bank spread
constexpr int NB   = 32;

__device__ __forceinline__ ushort f2bf(float f) {
    union { float f; uint u; } v; v.f = f;
    uint r = v.u + 0x7FFFu + ((v.u >> 16) & 1u);   // round-to-nearest-even
    return (ushort)(r >> 16);
}

__device__ __forceinline__ int tap_to_t(int q) {
    int t = (q < PAD) ? q : ((q < Lseq + PAD) ? q - PAD : q - 2 * PAD);
    return t > Lseq - 1 ? Lseq - 1 : t;   // clamped taps always meet zero weights
}

__global__ __launch_bounds__(256) void lll_one(const float* __restrict__ x,
                                               const float* __restrict__ W,
                                               const float* __restrict__ bias,
                                               float* __restrict__ out) {
    __shared__ ushort x_lds[C * PLX];              // 23.0 KB

    const int bid   = blockIdx.x;
    const int tile  = bid >> 5;                    // tile-major: bid+-32 = halo neighbor,
    const int b     = bid & 31;                    //  same XCD slot -> L2 reuse
    const int blk_o = tile * O_B;

    const int lane = threadIdx.x & 63;
    const int w    = threadIdx.x >> 6;
    const int m    = lane & 15;
    const int quad = lane >> 4;

    // ---- A-bake in registers: 2 tiles x 2 kappa-chunks, 8 elems each ----
    // lane needs W[o][j0+e], j0 = cch*32 + quad*8 - m, masked to j in [0,25).
    short8 afrag[2][2];
#pragma unroll
    for (int it = 0; it < 2; ++it) {
        const int o = blk_o + (w * 2 + it) * 16 + m;
        const size_t rowb = (size_t)o * 4121;      // W[o][o+j] = W_flat[o*4121 + j]
#pragma unroll
        for (int cch = 0; cch < 2; ++cch) {
            const int j0 = cch * 32 + quad * 8 - m;
            float v[8];
#pragma unroll
            for (int e = 0; e < 8; ++e) {
                const int j  = j0 + e;
                const int jc = min(max(j, 0), WIN - 1);    // always-valid address
                const float f = W[rowb + jc];              // L1/L2-hit (band resident)
                v[e] = (j == jc) ? f : 0.f;
            }
            short8 pk;
#pragma unroll
            for (int e = 0; e < 8; ++e) pk[e] = (short)f2bf(v[e]);
            afrag[it][cch] = pk;
        }
    }

    // ---- stage x -> x_lds[c][p] bf16, 8-tap units, b128 LDS writes ----
    const float4* xb = (const float4*)(x + (size_t)b * Lseq * C);
#pragma unroll
    for (int s = 0; s < 2; ++s) {
        const int u = threadIdx.x + 256 * s;
        if (u < 16 * (PWIN / 8)) {                 // 352 units: (c4, tap-oct)
            const int c4 = u & 15, oct = u >> 4, p0 = oct * 8;
            float4 f[8];
#pragma unroll
            for (int i = 0; i < 8; ++i)
                f[i] = xb[(size_t)tap_to_t(blk_o + p0 + i) * 16 + c4];
#pragma unroll
            for (int ch = 0; ch < 4; ++ch) {
                short8 pk;
#pragma unroll
                for (int i = 0; i < 8; ++i) {
                    const float v = (ch == 0) ? f[i].x : (ch == 1) ? f[i].y
                                  : (ch == 2) ? f[i].z : f[i].w;
                    pk[i] = (short)f2bf(v);
                }
                *(short8*)&x_lds[(c4 * 4 + ch) * PLX + p0] = pk;
            }
        }
    }
    __syncthreads();

    // ---- compute: 2 tiles/wave; operand-swapped MFMA -> contiguous stores ----
#pragma unroll
    for (int it = 0; it < 2; ++it) {
        const int t16 = w * 2 + it;
        const int o0  = blk_o + t16 * 16;
        const float bv = bias[o0 + m];             // out row o0+m, all channels

        f32x4 acc[4];
#pragma unroll
        for (int g = 0; g < 4; ++g)
#pragma unroll
            for (int r = 0; r < 4; ++r) acc[g][r] = bv;

#pragma unroll
        for (int cch = 0; cch < 2; ++cch) {
            const int poff = t16 * 16 + cch * 32 + quad * 8;
#pragma unroll
            for (int g = 0; g < 4; ++g) {
                // A-operand = x (row=channel 16g+m), B-operand = W (col=output o0+m)
                short8 xf = *(const short8*)&x_lds[(m + 16 * g) * PLX + poff];
                acc[g] = __builtin_amdgcn_mfma_f32_16x16x32_bf16(xf, afrag[it][cch],
                                                                 acc[g], 0, 0, 0);
            }
        }

        // D[row=16g+quad*4+r][col=m] -> out[o0+m][16g+quad*4+r]: contiguous x4
        float* op = out + (size_t)b * Lseq * C + (size_t)(o0 + m) * C;
#pragma unroll
        for (int g = 0; g < 4; ++g)
            *(f32x4*)(op + 16 * g + quad * 4) = acc[g];
    }
}

extern "C" void kernel_launch(void* const* d_in, const int* in_sizes, int n_in,
                              void* d_out, int out_size, void* d_ws, size_t ws_size,
                              hipStream_t stream) {
    const float* x    = (const float*)d_in[0];
    const float* W    = (const float*)d_in[1];
    const float* bias = (const float*)d_in[2];
    float*       out  = (float*)d_out;

    lll_one<<<NB * (Lseq / O_B), 256, 0, stream>>>(x, W, bias, out);  // 1024 blocks
}

// Round 8
// 24.122 us; speedup vs baseline: 1.0478x; 1.0478x over previous
//
#include <hip/hip_runtime.h>

// LocalLinearLayer via banded bf16 MFMA, fragment-major pre-baked weights,
// operand-SWAPPED MFMA (x as A, W as B) for contiguous dwordx4 stores.
//
// out[b,o,c] = bias[o] + sum_{j=0..24} W[o, o+j] * xp[b, o+j, c]
// xp[q] = x[q] (q<12), x[q-12] (12<=q<4108), x[q-24] (q>=4108)
//
// Per 16-output tile at o0 (gt=o0/16), kappa in [0,64), channel group g:
//   D_g[i=ch 16g+i'][j=o0+j'] = sum_kappa A_g[i][kappa] * B[kappa][j]
//   A_g[i][kappa] = xp[o0+kappa][16g+i]   (from x_lds, transposed)
//   B[kappa][j]   = W[o0+j', kappa-j'] if 0<=kappa-j'<25 else 0
// B-fragment (lane m,quad holds B[cch*32+quad*8+e][m] = W[o0+m][cch*32+quad*8+e-m])
// is EXACTLY akg2's fragment-major layout -> one coalesced 1KB b128 load.
// D: lane (m,quad) reg r = out[o0+m][16g+quad*4+r] -> f32x4 store per g.

typedef __attribute__((ext_vector_type(8))) short short8;
typedef __attribute__((ext_vector_type(4))) float f32x4;

constexpr int Lseq = 4096;
constexpr int C    = 64;
constexpr int WIN  = 25;
constexpr int PAD  = 12;
constexpr int O_B  = 128;          // outputs per block (4 waves x 2 tiles x 16)
constexpr int PWIN = 176;          // taps staged (128 + 48 halo)
constexpr int PLX  = 184;          // x_lds row stride (shorts); non-pow2 bank spread
constexpr int NB   = 32;
constexpr int NGT  = Lseq / 16;    // 256 global 16-tiles
constexpr size_t WS_NEEDED = (size_t)NGT * 2 * 64 * 8 * sizeof(ushort);  // 512 KB

__device__ __forceinline__ ushort f2bf(float f) {
    union { float f; uint u; } v; v.f = f;
    uint r = v.u + 0x7FFFu + ((v.u >> 16) & 1u);   // round-to-nearest-even
    return (ushort)(r >> 16);
}

__device__ __forceinline__ int tap_to_t(int q) {
    int t = (q < PAD) ? q : ((q < Lseq + PAD) ? q - PAD : q - 2 * PAD);
    return t > Lseq - 1 ? Lseq - 1 : t;   // clamped taps always meet zero weights
}

// ---- bake W band into fragment-major bf16 layout (512 KB, coalesced writes) ----
__global__ __launch_bounds__(256) void bake_frag(const float* __restrict__ W,
                                                 ushort* __restrict__ akg2) {
    const int gid  = blockIdx.x * 256 + threadIdx.x;   // 128 blocks -> 32768 frags
    const int gt   = gid >> 7;
    const int cch  = (gid >> 6) & 1;
    const int lane = gid & 63;
    const int m    = lane & 15, quad = lane >> 4;
    const int o    = gt * 16 + m;
    const int kb   = cch * 32 + quad * 8;
    short8 v;
#pragma unroll
    for (int e = 0; e < 8; ++e) {
        const int j = kb + e - m;
        float f = (j >= 0 && j < WIN) ? W[(size_t)o * 4121 + j] : 0.f;  // W[o][o+j]
        v[e] = (short)f2bf(f);
    }
    *(short8*)(akg2 + (size_t)gid * 8) = v;
}

// ---- main kernel: 256 threads, 128 outputs/block, one batch ----
__global__ __launch_bounds__(256) void lll_mfma(const float* __restrict__ x,
                                                const ushort* __restrict__ akg2,
                                                const float* __restrict__ bias,
                                                float* __restrict__ out) {
    __shared__ ushort x_lds[C * PLX];              // 23.0 KB

    const int bid   = blockIdx.x;
    const int tile  = bid >> 5;                    // consecutive bids: same tile, diff batch
    const int b     = bid & 31;                    // halo neighbors at bid+-32 -> same XCD slot
    const int blk_o = tile * O_B;

    const int lane = threadIdx.x & 63;
    const int w    = threadIdx.x >> 6;
    const int m    = lane & 15;
    const int quad = lane >> 4;

    // ---- prefetch W fragments (coalesced 1KB loads; in flight during staging) ----
    short8 afrag[2][2];
#pragma unroll
    for (int it = 0; it < 2; ++it) {
        const int gt = tile * 8 + w * 2 + it;
#pragma unroll
        for (int cch = 0; cch < 2; ++cch)
            afrag[it][cch] =
                *(const short8*)(akg2 + ((size_t)(gt * 2 + cch) * 64 + lane) * 8);
    }

    // ---- stage x -> x_lds[c][p] bf16, 8-tap units, b128 LDS writes ----
    const float4* xb = (const float4*)(x + (size_t)b * Lseq * C);
#pragma unroll
    for (int s = 0; s < 2; ++s) {
        const int u = threadIdx.x + 256 * s;
        if (u < 16 * (PWIN / 8)) {                 // 352 units: (c4, tap-oct)
            const int c4 = u & 15, oct = u >> 4, p0 = oct * 8;
            float4 f[8];
#pragma unroll
            for (int i = 0; i < 8; ++i)
                f[i] = xb[(size_t)tap_to_t(blk_o + p0 + i) * 16 + c4];
#pragma unroll
            for (int ch = 0; ch < 4; ++ch) {
                short8 pk;
#pragma unroll
                for (int i = 0; i < 8; ++i) {
                    const float v = (ch == 0) ? f[i].x : (ch == 1) ? f[i].y
                                  : (ch == 2) ? f[i].z : f[i].w;
                    pk[i] = (short)f2bf(v);
                }
                *(short8*)&x_lds[(c4 * 4 + ch) * PLX + p0] = pk;
            }
        }
    }
    __syncthreads();

    // ---- compute: 2 tiles/wave, swapped operands; contiguous x4 stores ----
#pragma unroll
    for (int it = 0; it < 2; ++it) {
        const int t16 = w * 2 + it;
        const int o0  = blk_o + t16 * 16;
        const float bv = bias[o0 + m];             // out row o0+m, all channels

        f32x4 acc[4];
#pragma unroll
        for (int g = 0; g < 4; ++g)
#pragma unroll
            for (int r = 0; r < 4; ++r) acc[g][r] = bv;

#pragma unroll
        for (int cch = 0; cch < 2; ++cch) {
            const int poff = t16 * 16 + cch * 32 + quad * 8;
#pragma unroll
            for (int g = 0; g < 4; ++g) {
                // A = x (rows = channels 16g+i), B = W (cols = outputs o0+j)
                short8 xf = *(const short8*)&x_lds[(m + 16 * g) * PLX + poff];
                acc[g] = __builtin_amdgcn_mfma_f32_16x16x32_bf16(xf, afrag[it][cch],
                                                                 acc[g], 0, 0, 0);
            }
        }

        // D: lane (m,quad) reg r -> out[o0+m][16g+quad*4+r]: 16B contiguous per g
        float* op = out + (size_t)b * Lseq * C + (size_t)(o0 + m) * C;
#pragma unroll
        for (int g = 0; g < 4; ++g)
            *(f32x4*)(op + 16 * g + quad * 4) = acc[g];
    }
}

// ---- fallback f32 path (ws too small; not expected) ----
constexpr int KO = 8, OG = 16, O_TILE = KO * OG, ROWS = KO + WIN - 1;

template <bool EDGE>
__device__ __forceinline__ void compute_tile_f32(
    const float4* __restrict__ x4b, const float* __restrict__ W,
    const float* __restrict__ bias, float4* __restrict__ out4b, int o0)
{
    float4 acc[KO];
#pragma unroll
    for (int k = 0; k < KO; ++k) { float bv = bias[o0 + k]; acc[k] = make_float4(bv, bv, bv, bv); }
    int wbase[KO];
#pragma unroll
    for (int k = 0; k < KO; ++k) wbase[k] = (o0 + k) * 4121 - k;
#pragma unroll
    for (int r = 0; r < ROWS; ++r) {
        const int p = o0 + r;
        int t = EDGE ? ((p < PAD) ? p : ((p < Lseq + PAD) ? p - PAD : p - 2 * PAD)) : (p - PAD);
        const float4 xv = x4b[(size_t)t * 16];
#pragma unroll
        for (int k = 0; k < KO; ++k) {
            const int j = r - k;
            if (j >= 0 && j < WIN) {
                const float w = W[(size_t)(wbase[k] + r)];
                acc[k].x = fmaf(w, xv.x, acc[k].x); acc[k].y = fmaf(w, xv.y, acc[k].y);
                acc[k].z = fmaf(w, xv.z, acc[k].z); acc[k].w = fmaf(w, xv.w, acc[k].w);
            }
        }
    }
#pragma unroll
    for (int k = 0; k < KO; ++k) out4b[(size_t)(o0 + k) * 16] = acc[k];
}

__global__ __launch_bounds__(256) void lll_f32(
    const float* __restrict__ x, const float* __restrict__ W,
    const float* __restrict__ bias, float* __restrict__ out)
{
    const int tid = threadIdx.x;
    const int tiles = Lseq / O_TILE;
    const int b = blockIdx.x / tiles, tile = blockIdx.x % tiles;
    const int o0 = tile * O_TILE + (tid >> 4) * KO;
    const int c4 = tid & 15;
    const float4* x4b = (const float4*)x + (size_t)b * Lseq * 16 + c4;
    float4* out4b = (float4*)out + (size_t)b * Lseq * 16 + c4;
    const bool interior = (o0 >= PAD) && (o0 + ROWS <= Lseq + PAD);
    if (interior) compute_tile_f32<false>(x4b, W, bias, out4b, o0);
    else          compute_tile_f32<true>(x4b, W, bias, out4b, o0);
}

extern "C" void kernel_launch(void* const* d_in, const int* in_sizes, int n_in,
                              void* d_out, int out_size, void* d_ws, size_t ws_size,
                              hipStream_t stream) {
    const float* x    = (const float*)d_in[0];
    const float* W    = (const float*)d_in[1];
    const float* bias = (const float*)d_in[2];
    float*       out  = (float*)d_out;

    if (ws_size >= WS_NEEDED) {
        ushort* akg2 = (ushort*)d_ws;
        bake_frag<<<NGT * 128 / 256, 256, 0, stream>>>(W, akg2);             // 128 blocks
        lll_mfma<<<NB * (Lseq / O_B), 256, 0, stream>>>(x, akg2, bias, out); // 1024 blocks
    } else {
        lll_f32<<<NB * (Lseq / O_TILE), 256, 0, stream>>>(x, W, bias, out);
    }
}

// Round 9
// 17.824 us; speedup vs baseline: 1.4180x; 1.3533x over previous
//
#include <hip/hip_runtime.h>

// LocalLinearLayer, SINGLE dispatch: banded bf16 MFMA.
// out[b,o,c] = bias[o] + sum_{j=0..24} W[o, o+j] * xp[b, o+j, c]
// xp[q] = x[q] (q<12), x[q-12] (12<=q<4108), x[q-24] (q>=4108)
//
// Per 16-output tile at o0, kappa in [0,64):
//   out[o0+m'][c] = sum_kappa A[m'][kappa] * B[kappa][c]
//   A[m'][kappa] = W[o0+m', kappa-m'] (0<=kappa-m'<25 else 0)
//   B[kappa][c]  = xp[o0+kappa][c]
// W band staged f32 into LDS with per-row coalesced loads (13 dwords/thread,
// 2 threads/row); each lane then gathers its 32 A-fragment values from LDS
// (predicated clamp+select) and packs bf16 in registers. One barrier total.
// Compute + store path identical to R6 (best measured variant).

typedef __attribute__((ext_vector_type(8))) short short8;
typedef __attribute__((ext_vector_type(4))) float f32x4;

constexpr int Lseq = 4096;
constexpr int C    = 64;
constexpr int WIN  = 25;
constexpr int PAD  = 12;
constexpr int O_B  = 128;          // outputs per block (4 waves x 2 tiles x 16)
constexpr int PWIN = 176;          // taps staged (128 + 48 halo)
constexpr int PLX  = 184;          // x_lds row stride (shorts); non-pow2 bank spread
constexpr int WROW = 28;           // w_band row stride (floats)
constexpr int NB   = 32;

__device__ __forceinline__ ushort f2bf(float f) {
    union { float f; uint u; } v; v.f = f;
    uint r = v.u + 0x7FFFu + ((v.u >> 16) & 1u);   // round-to-nearest-even
    return (ushort)(r >> 16);
}

__device__ __forceinline__ int tap_to_t(int q) {
    int t = (q < PAD) ? q : ((q < Lseq + PAD) ? q - PAD : q - 2 * PAD);
    return t > Lseq - 1 ? Lseq - 1 : t;   // clamped taps always meet zero weights
}

__global__ __launch_bounds__(256) void lll_one(const float* __restrict__ x,
                                               const float* __restrict__ W,
                                               const float* __restrict__ bias,
                                               float* __restrict__ out) {
    __shared__ ushort x_lds[C * PLX];        // 23.5 KB: x bf16, [channel][tap]
    __shared__ float  w_band[O_B * WROW];    // 14.3 KB: raw band rows, f32

    const int bid   = blockIdx.x;
    const int tile  = bid >> 5;              // tile-major: bid+-32 = halo neighbor
    const int b     = bid & 31;
    const int blk_o = tile * O_B;

    const int tid  = threadIdx.x;
    const int lane = tid & 63;
    const int w    = tid >> 6;
    const int m    = lane & 15;
    const int quad = lane >> 4;

    // ---- stage W band rows -> LDS, f32, per-row coalesced ----
    // thread t: relative row t>>1, half h=t&1 covers j = h*12 .. h*12+12
    // (j=12 written twice with identical data; max index (blk_o+127)*4121+24 in range)
    {
        const int row = tid >> 1, h = tid & 1;
        const float* wr = W + (size_t)(blk_o + row) * 4121 + h * 12;
        float v[13];
#pragma unroll
        for (int i = 0; i < 13; ++i) v[i] = wr[i];
        float* dst = &w_band[row * WROW + h * 12];
#pragma unroll
        for (int i = 0; i < 13; ++i) dst[i] = v[i];
    }

    // ---- stage x -> x_lds[c][p] bf16, 8-tap units, b128 LDS writes ----
    const float4* xb = (const float4*)(x + (size_t)b * Lseq * C);
#pragma unroll
    for (int s = 0; s < 2; ++s) {
        const int u = tid + 256 * s;
        if (u < 16 * (PWIN / 8)) {           // 352 units: (c4, tap-oct)
            const int c4 = u & 15, oct = u >> 4, p0 = oct * 8;
            float4 f[8];
#pragma unroll
            for (int i = 0; i < 8; ++i)
                f[i] = xb[(size_t)tap_to_t(blk_o + p0 + i) * 16 + c4];
#pragma unroll
            for (int ch = 0; ch < 4; ++ch) {
                short8 pk;
#pragma unroll
                for (int i = 0; i < 8; ++i) {
                    const float v = (ch == 0) ? f[i].x : (ch == 1) ? f[i].y
                                  : (ch == 2) ? f[i].z : f[i].w;
                    pk[i] = (short)f2bf(v);
                }
                *(short8*)&x_lds[(c4 * 4 + ch) * PLX + p0] = pk;
            }
        }
    }
    __syncthreads();

    // ---- gather A-fragments from w_band (LDS), pack bf16 in registers ----
    short8 afrag[2][2];
#pragma unroll
    for (int it = 0; it < 2; ++it) {
        const int row = (w * 2 + it) * 16 + m;            // relative band row
#pragma unroll
        for (int cch = 0; cch < 2; ++cch) {
            const int j0 = cch * 32 + quad * 8 - m;
            short8 pk;
#pragma unroll
            for (int e = 0; e < 8; ++e) {
                const int j  = j0 + e;
                const int jc = min(max(j, 0), WIN - 1);
                const float f = w_band[row * WROW + jc];
                pk[e] = (short)f2bf((j == jc) ? f : 0.f);
            }
            afrag[it][cch] = pk;
        }
    }

    // ---- compute: 2 tiles/wave (R6 verbatim) ----
    float* ob = out + (size_t)b * Lseq * C;
#pragma unroll
    for (int it = 0; it < 2; ++it) {
        const int t16 = w * 2 + it;
        const int o0  = blk_o + t16 * 16;

        f32x4 acc[4];
        {
            const float4 bv = *((const float4*)(bias + o0) + quad);
            const float bb[4] = {bv.x, bv.y, bv.z, bv.w};
#pragma unroll
            for (int r = 0; r < 4; ++r)
#pragma unroll
                for (int g = 0; g < 4; ++g) acc[g][r] = bb[r];
        }

#pragma unroll
        for (int cch = 0; cch < 2; ++cch) {
            const int poff = t16 * 16 + cch * 32 + quad * 8;
#pragma unroll
            for (int g = 0; g < 4; ++g) {
                short8 bf = *(const short8*)&x_lds[(m + 16 * g) * PLX + poff];
                acc[g] = __builtin_amdgcn_mfma_f32_16x16x32_bf16(afrag[it][cch], bf,
                                                                 acc[g], 0, 0, 0);
            }
        }

#pragma unroll
        for (int g = 0; g < 4; ++g)
#pragma unroll
            for (int r = 0; r < 4; ++r)
                ob[(size_t)(o0 + quad * 4 + r) * C + m + 16 * g] = acc[g][r];
    }
}

extern "C" void kernel_launch(void* const* d_in, const int* in_sizes, int n_in,
                              void* d_out, int out_size, void* d_ws, size_t ws_size,
                              hipStream_t stream) {
    const float* x    = (const float*)d_in[0];
    const float* W    = (const float*)d_in[1];
    const float* bias = (const float*)d_in[2];
    float*       out  = (float*)d_out;

    lll_one<<<NB * (Lseq / O_B), 256, 0, stream>>>(x, W, bias, out);  // 1024 blocks
}